// Round 1
// baseline (1182.106 us; speedup 1.0000x reference)
//
#include <hip/hip_runtime.h>
#include <stdint.h>
#include <math.h>

#define HID 64
#define DIN 128
#define DOUT 40
#define N_LAYERS 8

static inline int cdiv(int a, int b) { return (a + b - 1) / b; }

// ---------- edge-index layout detection (int32 vs int64 storage) ----------
__global__ void detect_i64(const uint32_t* __restrict__ ei, int* __restrict__ flag) {
    int t = threadIdx.x;                 // 64 threads
    uint32_t w = ei[2 * t + 1];          // upper words if int64, odd src entries if int32
    unsigned long long nz = __ballot(w != 0u);
    if (t == 0) *flag = (nz == 0ull) ? 1 : 0;
}

__device__ __forceinline__ int edge_src(const uint32_t* ei, int is64, int E, int e) {
    return is64 ? (int)ei[2 * e] : (int)ei[e];
}
__device__ __forceinline__ int edge_dst(const uint32_t* ei, int is64, int E, int e) {
    return is64 ? (int)ei[2 * (size_t)E + 2 * e] : (int)ei[(size_t)E + e];
}

// ---------- CSR construction ----------
__global__ void init_cnt(int* __restrict__ cnt, int n) {
    int v = blockIdx.x * blockDim.x + threadIdx.x;
    if (v < n) cnt[v] = 0;
}

__global__ void count_deg(const uint32_t* __restrict__ ei, const int* __restrict__ flag,
                          int* __restrict__ cnt, int E) {
    int e = blockIdx.x * blockDim.x + threadIdx.x;
    if (e >= E) return;
    int is64 = *flag;
    atomicAdd(&cnt[edge_dst(ei, is64, E, e)], 1);
}

__global__ void scan1(const int* __restrict__ cnt, int* __restrict__ row_start,
                      int* __restrict__ blocksum, int n) {
    __shared__ int sh[256];
    int t = threadIdx.x;
    int v = blockIdx.x * 256 + t;
    int val = (v < n) ? cnt[v] : 0;
    sh[t] = val;
    __syncthreads();
    for (int o = 1; o < 256; o <<= 1) {
        int y = (t >= o) ? sh[t - o] : 0;
        __syncthreads();
        sh[t] += y;
        __syncthreads();
    }
    if (v < n) row_start[v] = sh[t] - val;     // exclusive within block
    if (t == 255) blocksum[blockIdx.x] = sh[255];
}

__global__ void scan2(int* __restrict__ blocksum, int nb) {
    __shared__ int sh[512];
    int t = threadIdx.x;
    int val = (t < nb) ? blocksum[t] : 0;
    sh[t] = val;
    __syncthreads();
    for (int o = 1; o < 512; o <<= 1) {
        int y = (t >= o) ? sh[t - o] : 0;
        __syncthreads();
        sh[t] += y;
        __syncthreads();
    }
    if (t < nb) blocksum[t] = sh[t] - val;     // exclusive
}

__global__ void scan3(int* __restrict__ row_start, const int* __restrict__ blocksum,
                      int* __restrict__ cursor, int n) {
    int v = blockIdx.x * 256 + threadIdx.x;
    if (v < n) {
        row_start[v] += blocksum[v >> 8];
        cursor[v] = 0;
    }
}

__global__ void compute_dinv(const int* __restrict__ cnt, float* __restrict__ dinv, int n) {
    int v = blockIdx.x * blockDim.x + threadIdx.x;
    if (v < n) dinv[v] = rsqrtf((float)(cnt[v] + 1));   // +1 self loop
}

__global__ void scatter_edges(const uint32_t* __restrict__ ei, const int* __restrict__ flag,
                              const int* __restrict__ row_start, int* __restrict__ cursor,
                              const float* __restrict__ dinv,
                              int* __restrict__ csr_src, float* __restrict__ csr_w, int E) {
    int e = blockIdx.x * blockDim.x + threadIdx.x;
    if (e >= E) return;
    int is64 = *flag;
    int s = edge_src(ei, is64, E, e);
    int d = edge_dst(ei, is64, E, e);
    int pos = row_start[d] + atomicAdd(&cursor[d], 1);
    csr_src[pos] = s;
    csr_w[pos] = dinv[s] * dinv[d];
}

// ---------- h0 = relu(x @ W1 + b1), duplicated into h ----------
__global__ void mlp_in(const float* __restrict__ x, const float* __restrict__ W1,
                       const float* __restrict__ b1,
                       float* __restrict__ h, float* __restrict__ h0, int n) {
    __shared__ float W1s[DIN * HID];      // 32 KB
    __shared__ float xs[16 * DIN];        // 8 KB
    int t = threadIdx.x;
    for (int i = t; i < DIN * HID; i += 256) W1s[i] = W1[i];
    int node0 = blockIdx.x * 16;
    for (int i = t; i < 16 * DIN; i += 256) {
        int node = node0 + (i >> 7);
        xs[i] = (node < n) ? x[(size_t)node0 * DIN + i] : 0.f;
    }
    __syncthreads();
    int f = t & 63, wv = t >> 6;
    float bias = b1[f];
    for (int k = 0; k < 4; k++) {
        int nloc = wv + 4 * k;
        int node = node0 + nloc;
        if (node >= n) continue;
        float dot = bias;
#pragma unroll 8
        for (int kk = 0; kk < DIN; kk++) dot += xs[nloc * DIN + kk] * W1s[kk * HID + f];
        float v = fmaxf(dot, 0.f);
        h[(size_t)node * HID + f] = v;
        h0[(size_t)node * HID + f] = v;
    }
}

// ---------- SpMM: out = 0.9 * (Ahat h) + 0.1 * h0 ; one wave per dst node ----------
__global__ void spmm(const float* __restrict__ h, const float* __restrict__ h0,
                     const int* __restrict__ row_start, const int* __restrict__ cnt,
                     const float* __restrict__ dinv,
                     const int* __restrict__ csr_src, const float* __restrict__ csr_w,
                     float* __restrict__ out, int n) {
    int wid = (blockIdx.x * blockDim.x + threadIdx.x) >> 6;
    int lane = threadIdx.x & 63;
    if (wid >= n) return;
    int v = wid;
    float dv = dinv[v];
    float acc = dv * dv * h[(size_t)v * HID + lane];   // self loop
    int start = row_start[v];
    int e = cnt[v];
    int j = start, end = start + e;
    for (; j + 4 <= end; j += 4) {
        int s0 = csr_src[j], s1 = csr_src[j + 1], s2 = csr_src[j + 2], s3 = csr_src[j + 3];
        float w0 = csr_w[j], w1 = csr_w[j + 1], w2 = csr_w[j + 2], w3 = csr_w[j + 3];
        float a0 = h[(size_t)s0 * HID + lane];
        float a1 = h[(size_t)s1 * HID + lane];
        float a2 = h[(size_t)s2 * HID + lane];
        float a3 = h[(size_t)s3 * HID + lane];
        acc += w0 * a0 + w1 * a1 + w2 * a2 + w3 * a3;
    }
    for (; j < end; ++j) acc += csr_w[j] * h[(size_t)csr_src[j] * HID + lane];
    out[(size_t)v * HID + lane] = 0.9f * acc + 0.1f * h0[(size_t)v * HID + lane];
}

// ---------- h = relu((1-beta)*out + beta*(out @ W_i)) ----------
__global__ void layer_mlp(const float* __restrict__ out, const float* __restrict__ W,
                          float beta, float* __restrict__ h, int n) {
    __shared__ __align__(16) float os[32 * HID];   // 8 KB
    int t = threadIdx.x;
    int f = t & 63, wv = t >> 6;
    float wc[64];                                  // W column f in registers
#pragma unroll
    for (int k = 0; k < 64; k++) wc[k] = W[k * HID + f];
    int node0 = blockIdx.x * 32;
    for (int i = t; i < 32 * HID; i += 256) {
        int node = node0 + (i >> 6);
        os[i] = (node < n) ? out[(size_t)node0 * HID + i] : 0.f;
    }
    __syncthreads();
    const float4* os4 = (const float4*)os;
    for (int k = 0; k < 8; k++) {
        int nloc = wv + 4 * k;
        int node = node0 + nloc;
        if (node >= n) continue;
        float dot = 0.f;
#pragma unroll
        for (int q = 0; q < 16; q++) {
            float4 o4 = os4[nloc * 16 + q];        // broadcast read
            dot += o4.x * wc[4 * q] + o4.y * wc[4 * q + 1] +
                   o4.z * wc[4 * q + 2] + o4.w * wc[4 * q + 3];
        }
        float o = os[nloc * HID + f];
        float val = (1.f - beta) * o + beta * dot;
        h[(size_t)node * HID + f] = fmaxf(val, 0.f);
    }
}

// ---------- y = h @ W2 + b2 ----------
__global__ void mlp_out(const float* __restrict__ h, const float* __restrict__ W2,
                        const float* __restrict__ b2, float* __restrict__ y, int n) {
    __shared__ float hs[32 * HID];        // 8 KB
    __shared__ float W2s[HID * DOUT];     // 10 KB
    __shared__ float b2s[DOUT];
    int t = threadIdx.x;
    for (int i = t; i < HID * DOUT; i += 256) W2s[i] = W2[i];
    if (t < DOUT) b2s[t] = b2[t];
    int node0 = blockIdx.x * 32;
    for (int i = t; i < 32 * HID; i += 256) {
        int node = node0 + (i >> 6);
        hs[i] = (node < n) ? h[(size_t)node0 * HID + i] : 0.f;
    }
    __syncthreads();
    for (int idx = t; idx < 32 * DOUT; idx += 256) {
        int nloc = idx / DOUT, fo = idx % DOUT;
        int node = node0 + nloc;
        if (node >= n) continue;
        float dot = b2s[fo];
#pragma unroll 8
        for (int k = 0; k < HID; k++) dot += hs[nloc * HID + k] * W2s[k * DOUT + fo];
        y[(size_t)node * DOUT + fo] = dot;
    }
}

extern "C" void kernel_launch(void* const* d_in, const int* in_sizes, int n_in,
                              void* d_out, int out_size, void* d_ws, size_t ws_size,
                              hipStream_t stream) {
    const float*    x     = (const float*)d_in[0];
    const uint32_t* ei    = (const uint32_t*)d_in[1];
    const float*    W1    = (const float*)d_in[2];
    const float*    b1    = (const float*)d_in[3];
    const float*    convw = (const float*)d_in[4];
    const float*    W2    = (const float*)d_in[5];
    const float*    b2    = (const float*)d_in[6];
    float*          y     = (float*)d_out;

    int N = in_sizes[0] / DIN;
    int E = in_sizes[1] / 2;

    char* ws = (char*)d_ws;
    size_t off = 0;
    auto alloc = [&](size_t bytes) -> char* {
        char* p = ws + off;
        off = (off + bytes + 255) & ~(size_t)255;
        return p;
    };
    int*   flag      = (int*)alloc(4);
    int*   cnt       = (int*)alloc((size_t)N * 4);
    int*   row_start = (int*)alloc((size_t)N * 4);
    int*   cursor    = (int*)alloc((size_t)N * 4);
    float* dinv      = (float*)alloc((size_t)N * 4);
    int*   blocksum  = (int*)alloc(512 * 4);
    int*   csr_src   = (int*)alloc((size_t)E * 4);
    float* csr_w     = (float*)alloc((size_t)E * 4);
    float* h         = (float*)alloc((size_t)N * HID * 4);
    float* h0        = (float*)alloc((size_t)N * HID * 4);
    float* outb      = (float*)alloc((size_t)N * HID * 4);

    detect_i64<<<1, 64, 0, stream>>>(ei, flag);
    init_cnt<<<cdiv(N, 256), 256, 0, stream>>>(cnt, N);
    count_deg<<<cdiv(E, 256), 256, 0, stream>>>(ei, flag, cnt, E);
    int nb = cdiv(N, 256);
    scan1<<<nb, 256, 0, stream>>>(cnt, row_start, blocksum, N);
    scan2<<<1, 512, 0, stream>>>(blocksum, nb);
    scan3<<<cdiv(N, 256), 256, 0, stream>>>(row_start, blocksum, cursor, N);
    compute_dinv<<<cdiv(N, 256), 256, 0, stream>>>(cnt, dinv, N);
    scatter_edges<<<cdiv(E, 256), 256, 0, stream>>>(ei, flag, row_start, cursor, dinv,
                                                    csr_src, csr_w, E);
    mlp_in<<<cdiv(N, 16), 256, 0, stream>>>(x, W1, b1, h, h0, N);
    for (int i = 0; i < N_LAYERS; i++) {
        spmm<<<cdiv(N, 4), 256, 0, stream>>>(h, h0, row_start, cnt, dinv,
                                             csr_src, csr_w, outb, N);
        float beta = logf(0.5f / (float)(i + 1) + 1.f);
        layer_mlp<<<cdiv(N, 32), 256, 0, stream>>>(outb, convw + (size_t)i * HID * HID,
                                                   beta, h, N);
    }
    mlp_out<<<cdiv(N, 32), 256, 0, stream>>>(h, W2, b2, y, N);
}